// Round 18
// baseline (218.225 us; speedup 1.0000x reference)
//
#include <hip/hip_runtime.h>
#include <math.h>

// Problem constants
constexpr int BN  = 16;    // batch
constexpr int HH  = 224;
constexpr int WW  = 224;
constexpr int CI  = 8;     // input channels
constexpr int FF  = 256;   // filter feature dim
constexpr int NC  = 16;    // output channels
constexpr int NP  = 1152;  // CI*NC*3*3 dynamic params per sample
// reference patch index p = cin*9 + dy*3 + dx ; w[b][p][c] = dyn[b][p*16+c]
// MFMA K-ordering: k = tap*8 + cin, tap = dy*3+dx (taps 9..11 pad=0)
//
// *** MEASUREMENT BUILD ***: k_h body x64, k_conv body x6 (idempotent reps,
// memory-clobber per rep) to force both kernels above the top-5 visibility
// threshold (~40 us, set by the harness's fillBuffer resets) and obtain
// per-kernel dur + counters. k_dyn is NOT repeated (atomics non-idempotent).
// Bodies otherwise byte-identical to round 17 (39.7 us best).

typedef __attribute__((ext_vector_type(8))) short short8;   // 8 bf16 = 4 VGPR
typedef __attribute__((ext_vector_type(4))) float f32x4;

__device__ __forceinline__ float elu_f(float x) {
    return x > 0.0f ? x : (__expf(x) - 1.0f);
}

// split f32 -> bf16 hi (truncate) + bf16 lo (residual, truncate): v ~= hi+lo
__device__ __forceinline__ void split8(const float* v, short8& hi, short8& lo) {
#pragma unroll
    for (int j = 0; j < 8; ++j) {
        const unsigned u = __float_as_uint(v[j]);
        hi[j] = (short)(u >> 16);
        const float hf = __uint_as_float(u & 0xffff0000u);
        lo[j] = (short)(__float_as_uint(v[j] - hf) >> 16);
    }
}

// -------- kernel 1: h partials, k-split x4 (hp[ks][b][col], pre-elu) ---------
// [r16-proven body] x64 reps for measurement.
__global__ __launch_bounds__(128) void k_h(const float* __restrict__ fi,
                                           const float* __restrict__ W1,
                                           const float* __restrict__ b1,
                                           const float* __restrict__ bd,
                                           const float* __restrict__ bb,
                                           const float* __restrict__ dfn,
                                           float* __restrict__ hp,
                                           float* __restrict__ w_out,
                                           float* __restrict__ bias_out) {
    __shared__ float x[64];
    const int bid  = blockIdx.x;
    const int b    = bid >> 3;
    const int half = (bid >> 2) & 1;
    const int ks   = bid & 3;
    const int t    = threadIdx.x;

#pragma unroll 1
    for (int rep = 0; rep < 64; ++rep) {
        if (t < 64) x[t] = fi[b * FF + ks * 64 + t];
        __syncthreads();

        const int col = half * 128 + t;
        float acc = (ks == 0) ? b1[col] : 0.0f;
#pragma unroll 8
        for (int k = 0; k < 64; ++k)
            acc = fmaf(x[k], W1[(ks * 64 + k) * FF + col], acc);
        hp[(ks * BN + b) * FF + col] = acc;

        // ---- init for k_dyn atomics ----
        const int gid = bid * 128 + t;           // 0..16383
        for (int i = gid; i < BN * NP; i += 16384) {
            const int c = i - (i / NP) * NP;
            w_out[i] = bd[c];
        }
        if (gid < BN * NC) bias_out[gid] = bb[gid & 15] + dfn[gid & 15];
        __syncthreads();
        asm volatile("" ::: "memory");
    }
}

// ------------- kernel 2: dyn += h@Wd ; bias += h@Wb (k-split atomics) --------
// [r12/r16-proven, unmodified — atomics are not idempotent, no reps]
__global__ __launch_bounds__(128) void k_dyn(const float* __restrict__ hp,
                                             const float* __restrict__ Wd,
                                             const float* __restrict__ Wb,
                                             float* __restrict__ w_out,
                                             float* __restrict__ bias_out) {
    __shared__ float hs[16][32];
    const int bid = blockIdx.x;
    const int cg  = bid % 9;                 // column group (128 cols)
    const int ks  = bid / 9;                 // k-split (32 k)
    const int k0  = ks * 32;
    const int t   = threadIdx.x;

#pragma unroll
    for (int j = 0; j < 4; ++j) {
        const int idx = t + 128 * j;         // 0..511
        const int bi = idx >> 5, kk = idx & 31;
        const int o = bi * FF + k0 + kk;
        const float s = hp[o] + hp[BN * FF + o] +
                        hp[2 * BN * FF + o] + hp[3 * BN * FF + o];
        hs[bi][kk] = elu_f(s);
    }
    __syncthreads();

    const int i = cg * 128 + t;              // output column < 1152
    float a[16];
#pragma unroll
    for (int b = 0; b < 16; ++b) a[b] = 0.0f;

#pragma unroll 8
    for (int kk = 0; kk < 32; ++kk) {
        const float w = Wd[(size_t)(k0 + kk) * NP + i];
#pragma unroll
        for (int b = 0; b < 16; ++b) a[b] = fmaf(hs[b][kk], w, a[b]);
    }
#pragma unroll
    for (int b = 0; b < 16; ++b) atomicAdd(&w_out[b * NP + i], a[b]);

    if (cg == 0) {                           // bias partials ride along here
#pragma unroll
        for (int r = 0; r < 2; ++r) {
            const int p = t + r * 128;       // 0..255
            const int b = p >> 4, c = p & 15;
            float s = 0.0f;
#pragma unroll 8
            for (int kk = 0; kk < 32; ++kk)
                s = fmaf(hs[b][kk], Wb[(size_t)(k0 + kk) * NC + c], s);
            atomicAdd(&bias_out[b * NC + c], s);
        }
    }
}

// ---------------- kernel 3: dynamic conv as per-sample MFMA GEMM -------------
// [r17 body] x6 reps for measurement.
__global__ __launch_bounds__(128) void k_conv(const float* __restrict__ in,
                                              const float* __restrict__ w_all,
                                              const float* __restrict__ bias_all,
                                              float* __restrict__ out) {
    __shared__ short8 lsA[4][116][2];        // [row][px][hi/lo] = 14,848 B

    const int b    = blockIdx.z;
    const int half = blockIdx.x;             // 0/1: x-half of the rows
    const int t    = threadIdx.x;
    const int wid  = t >> 6;
    const int lane = t & 63;
    const int cl   = lane & 15;
    const int g    = lane >> 4;              // k-group 0..3
    const int yb0  = blockIdx.y * 2;
    const int xb0  = half * 112;

#pragma unroll 1
    for (int rep = 0; rep < 6; ++rep) {
        // ---- stage 4 rows x 114 px (hi/lo pre-split, zero-filled halo) ----
        for (int s = t; s < 456; s += 128) {
            const int r  = s / 114;
            const int j  = s - r * 114;
            const int gy = yb0 - 1 + r;
            const int gx = xb0 - 1 + j;
            const bool ok = ((unsigned)gy < (unsigned)HH) &&
                            ((unsigned)gx < (unsigned)WW);
            float av[8] = {0.f, 0.f, 0.f, 0.f, 0.f, 0.f, 0.f, 0.f};
            if (ok) {
                const float4* pp =
                    (const float4*)(in + ((size_t)(b * HH + gy) * WW + gx) * CI);
                const float4 a0 = pp[0];
                const float4 a1 = pp[1];
                av[0] = a0.x; av[1] = a0.y; av[2] = a0.z; av[3] = a0.w;
                av[4] = a1.x; av[5] = a1.y; av[6] = a1.z; av[7] = a1.w;
            }
            short8 hi, lo;
            split8(av, hi, lo);
            lsA[r][j][0] = hi;
            lsA[r][j][1] = lo;
        }

        // ---- per-lane tap geometry for the 3 k-chunks ----
        int  dyL[3], dxL[3];
        bool real[3];
#pragma unroll
        for (int c = 0; c < 3; ++c) {
            const int tap = c * 4 + g;
            real[c] = (tap < 9);
            const int tp = real[c] ? tap : 0;
            dyL[c] = tp / 3;
            dxL[c] = tp - 3 * dyL[c];
        }

        // ---- weight fragments (hi/lo), loaded once per wave ----
        const float* __restrict__ wq = w_all + b * NP;
        short8 bhi0, blo0, bhi1, blo1, bhi2, blo2;
        {
            float wv[8];
#pragma unroll
            for (int i = 0; i < 8; ++i)
                wv[i] = real[0] ? wq[(i * 9 + (0 * 4 + g)) * NC + cl] : 0.0f;
            split8(wv, bhi0, blo0);
#pragma unroll
            for (int i = 0; i < 8; ++i)
                wv[i] = real[1] ? wq[(i * 9 + (1 * 4 + g)) * NC + cl] : 0.0f;
            split8(wv, bhi1, blo1);
#pragma unroll
            for (int i = 0; i < 8; ++i)
                wv[i] = real[2] ? wq[(i * 9 + (2 * 4 + g)) * NC + cl] : 0.0f;
            split8(wv, bhi2, blo2);
        }

        __syncthreads();

        const float4 bias4 = ((const float4*)(bias_all + b * NC))[g];
        const int y = yb0 + wid;
        const size_t orow = ((size_t)(b * HH + y) * WW) * NC;

#pragma unroll 1
        for (int tx = 0; tx < 7; ++tx) {
            const int x0 = xb0 + tx * 16;
            f32x4 accM = {bias4.x, bias4.y, bias4.z, bias4.w};   // hi*hi
            f32x4 accL = {0.f, 0.f, 0.f, 0.f};                   // hiW*loA
            f32x4 accH = {0.f, 0.f, 0.f, 0.f};                   // loW*hiA

#pragma unroll
            for (int c = 0; c < 3; ++c) {
                const int j = tx * 16 + cl + dxL[c];             // 0..113
                const int r = wid + dyL[c];                      // 0..3
                const short8 ahi = lsA[r][j][0];
                const short8 alo = lsA[r][j][1];
                const short8 bh = (c == 0) ? bhi0 : (c == 1) ? bhi1 : bhi2;
                const short8 bl = (c == 0) ? blo0 : (c == 1) ? blo1 : blo2;
                accM = __builtin_amdgcn_mfma_f32_16x16x32_bf16(bh, ahi, accM, 0, 0, 0);
                accL = __builtin_amdgcn_mfma_f32_16x16x32_bf16(bh, alo, accL, 0, 0, 0);
                accH = __builtin_amdgcn_mfma_f32_16x16x32_bf16(bl, ahi, accH, 0, 0, 0);
            }

            float4 res;
            res.x = elu_f(accM[0] + accL[0] + accH[0]);
            res.y = elu_f(accM[1] + accL[1] + accH[1]);
            res.z = elu_f(accM[2] + accL[2] + accH[2]);
            res.w = elu_f(accM[3] + accL[3] + accH[3]);
            ((float4*)(out + orow + (size_t)(x0 + cl) * NC))[g] = res;
        }

        __syncthreads();
        asm volatile("" ::: "memory");
    }
}

extern "C" void kernel_launch(void* const* d_in, const int* in_sizes, int n_in,
                              void* d_out, int out_size, void* d_ws, size_t ws_size,
                              hipStream_t stream) {
    const float* inpt = (const float*)d_in[0];
    const float* fi   = (const float*)d_in[1];
    const float* W1   = (const float*)d_in[2];
    const float* b1   = (const float*)d_in[3];
    const float* Wd   = (const float*)d_in[4];
    const float* bd   = (const float*)d_in[5];
    const float* Wb   = (const float*)d_in[6];
    const float* bb   = (const float*)d_in[7];
    const float* dfn  = (const float*)d_in[8];
    float* out = (float*)d_out;

    float* ws    = (float*)d_ws;
    float* hp    = ws;                        // 4*16*256 = 16384 floats
    float* wDyn  = ws + 16384;                // 16*1152  = 18432 floats
    float* biasA = ws + 16384 + 18432;        // 16*16    = 256 floats

    k_h  <<<128, 128, 0, stream>>>(fi, W1, b1, bd, bb, dfn, hp, wDyn, biasA);
    k_dyn<<<72, 128, 0, stream>>>(hp, Wd, Wb, wDyn, biasA);
    k_conv<<<dim3(2, 112, BN), 128, 0, stream>>>(inpt, wDyn, biasA, out);
}

// Round 19
// 46.295 us; speedup vs baseline: 4.7138x; 4.7138x over previous
//
#include <hip/hip_runtime.h>
#include <math.h>

// Problem constants
constexpr int BN  = 16;    // batch
constexpr int HH  = 224;
constexpr int WW  = 224;
constexpr int CI  = 8;     // input channels
constexpr int FF  = 256;   // filter feature dim
constexpr int NC  = 16;    // output channels
constexpr int NP  = 1152;  // CI*NC*3*3 dynamic params per sample
// reference patch index p = cin*9 + dy*3 + dx ; w[b][p][c] = dyn[b][p*16+c]
// MFMA K-ordering: k = tap*8 + cin, tap = dy*3+dx (taps 9..11 pad=0)
//
// Budget (measured, r18 rep-build): k_h 1.7 us, k_conv 14.3 us (~1.15x its
// memory floor), k_dyn+gaps+fixed ~23.7 us. This round fuses k_h+k_dyn into
// one launch via an intra-kernel producer->consumer flag barrier (all 128
// blocks co-resident -> deadlock-free), removing one ~6-7 us launch boundary.

typedef __attribute__((ext_vector_type(8))) short short8;   // 8 bf16 = 4 VGPR
typedef __attribute__((ext_vector_type(4))) float f32x4;

constexpr unsigned MAGIC = 0x73E1D00Du;

__device__ __forceinline__ float elu_f(float x) {
    return x > 0.0f ? x : (__expf(x) - 1.0f);
}

// split f32 -> bf16 hi (truncate) + bf16 lo (residual, truncate): v ~= hi+lo
__device__ __forceinline__ void split8(const float* v, short8& hi, short8& lo) {
#pragma unroll
    for (int j = 0; j < 8; ++j) {
        const unsigned u = __float_as_uint(v[j]);
        hi[j] = (short)(u >> 16);
        const float hf = __uint_as_float(u & 0xffff0000u);
        lo[j] = (short)(__float_as_uint(v[j] - hf) >> 16);
    }
}

// ---- fused kernel 1+2: h partials (all 128 blocks) -> flag barrier ->
//      dyn/bias atomics (blocks 0..71). Bodies byte-identical to r16. -------
__global__ __launch_bounds__(128) void k_hd(const float* __restrict__ fi,
                                            const float* __restrict__ W1,
                                            const float* __restrict__ b1,
                                            const float* __restrict__ bd,
                                            const float* __restrict__ bb,
                                            const float* __restrict__ dfn,
                                            const float* __restrict__ Wd,
                                            const float* __restrict__ Wb,
                                            float* __restrict__ hp,
                                            float* __restrict__ w_out,
                                            float* __restrict__ bias_out,
                                            unsigned* __restrict__ flags) {
    __shared__ float x[64];
    __shared__ float hs[16][32];
    const int bid  = blockIdx.x;
    const int b    = bid >> 3;
    const int half = (bid >> 2) & 1;
    const int ks   = bid & 3;
    const int t    = threadIdx.x;

    // ---------------- phase 1: h partial (r16 k_h body) ----------------
    if (t < 64) x[t] = fi[b * FF + ks * 64 + t];
    __syncthreads();

    const int col = half * 128 + t;
    float acc = (ks == 0) ? b1[col] : 0.0f;
#pragma unroll 8
    for (int k = 0; k < 64; ++k)
        acc = fmaf(x[k], W1[(ks * 64 + k) * FF + col], acc);
    hp[(ks * BN + b) * FF + col] = acc;

    // init for phase-2 atomics
    const int gid = bid * 128 + t;           // 0..16383
    for (int i = gid; i < BN * NP; i += 16384) {
        const int c = i - (i / NP) * NP;
        w_out[i] = bd[c];
    }
    if (gid < BN * NC) bias_out[gid] = bb[gid & 15] + dfn[gid & 15];

    // ---------------- flag barrier (producer release) ----------------
    __syncthreads();
    if (t == 0) {
        __threadfence();
        __hip_atomic_store(&flags[bid], MAGIC, __ATOMIC_RELEASE,
                           __HIP_MEMORY_SCOPE_AGENT);
    }

    if (bid >= 72) return;                   // extra blocks done

    // consumer acquire: wait until all 128 producer flags are set
    bool ok;
    do {
        ok = (__hip_atomic_load(&flags[t], __ATOMIC_ACQUIRE,
                                __HIP_MEMORY_SCOPE_AGENT) == MAGIC);
    } while (!__syncthreads_and(ok));
    __threadfence();

    // ---------------- phase 2: dyn/bias atomics (r16 k_dyn body) -----------
    const int cg = bid % 9;                  // column group (128 cols)
    const int k2 = bid / 9;                  // k-split (32 k)
    const int k0 = k2 * 32;

#pragma unroll
    for (int j = 0; j < 4; ++j) {
        const int idx = t + 128 * j;         // 0..511
        const int bi = idx >> 5, kk = idx & 31;
        const int o = bi * FF + k0 + kk;
        const float s = hp[o] + hp[BN * FF + o] +
                        hp[2 * BN * FF + o] + hp[3 * BN * FF + o];
        hs[bi][kk] = elu_f(s);
    }
    __syncthreads();

    const int i = cg * 128 + t;              // output column < 1152
    float a[16];
#pragma unroll
    for (int bb2 = 0; bb2 < 16; ++bb2) a[bb2] = 0.0f;

#pragma unroll 8
    for (int kk = 0; kk < 32; ++kk) {
        const float w = Wd[(size_t)(k0 + kk) * NP + i];
#pragma unroll
        for (int bb2 = 0; bb2 < 16; ++bb2) a[bb2] = fmaf(hs[bb2][kk], w, a[bb2]);
    }
#pragma unroll
    for (int bb2 = 0; bb2 < 16; ++bb2) atomicAdd(&w_out[bb2 * NP + i], a[bb2]);

    if (cg == 0) {                           // bias partials ride along here
#pragma unroll
        for (int r = 0; r < 2; ++r) {
            const int p = t + r * 128;       // 0..255
            const int bi = p >> 4, c = p & 15;
            float s = 0.0f;
#pragma unroll 8
            for (int kk = 0; kk < 32; ++kk)
                s = fmaf(hs[bi][kk], Wb[(size_t)(k0 + kk) * NC + c], s);
            atomicAdd(&bias_out[bi * NC + c], s);
        }
    }
}

// ---------------- kernel 3: dynamic conv as per-sample MFMA GEMM -------------
// [r17 body, measured ~14.3 us ~ 1.15x memory floor — unchanged]
__global__ __launch_bounds__(128) void k_conv(const float* __restrict__ in,
                                              const float* __restrict__ w_all,
                                              const float* __restrict__ bias_all,
                                              float* __restrict__ out) {
    __shared__ short8 lsA[4][116][2];        // [row][px][hi/lo] = 14,848 B

    const int b    = blockIdx.z;
    const int half = blockIdx.x;             // 0/1: x-half of the rows
    const int t    = threadIdx.x;
    const int wid  = t >> 6;
    const int lane = t & 63;
    const int cl   = lane & 15;
    const int g    = lane >> 4;              // k-group 0..3
    const int yb0  = blockIdx.y * 2;
    const int xb0  = half * 112;

    // ---- stage 4 rows x 114 px (hi/lo pre-split, zero-filled halo) ----
    for (int s = t; s < 456; s += 128) {
        const int r  = s / 114;
        const int j  = s - r * 114;
        const int gy = yb0 - 1 + r;
        const int gx = xb0 - 1 + j;
        const bool ok = ((unsigned)gy < (unsigned)HH) &&
                        ((unsigned)gx < (unsigned)WW);
        float av[8] = {0.f, 0.f, 0.f, 0.f, 0.f, 0.f, 0.f, 0.f};
        if (ok) {
            const float4* pp =
                (const float4*)(in + ((size_t)(b * HH + gy) * WW + gx) * CI);
            const float4 a0 = pp[0];
            const float4 a1 = pp[1];
            av[0] = a0.x; av[1] = a0.y; av[2] = a0.z; av[3] = a0.w;
            av[4] = a1.x; av[5] = a1.y; av[6] = a1.z; av[7] = a1.w;
        }
        short8 hi, lo;
        split8(av, hi, lo);
        lsA[r][j][0] = hi;
        lsA[r][j][1] = lo;
    }

    // ---- per-lane tap geometry for the 3 k-chunks ----
    int  dyL[3], dxL[3];
    bool real[3];
#pragma unroll
    for (int c = 0; c < 3; ++c) {
        const int tap = c * 4 + g;
        real[c] = (tap < 9);
        const int tp = real[c] ? tap : 0;
        dyL[c] = tp / 3;
        dxL[c] = tp - 3 * dyL[c];
    }

    // ---- weight fragments (hi/lo), loaded once per wave ----
    const float* __restrict__ wq = w_all + b * NP;
    short8 bhi0, blo0, bhi1, blo1, bhi2, blo2;
    {
        float wv[8];
#pragma unroll
        for (int i = 0; i < 8; ++i)
            wv[i] = real[0] ? wq[(i * 9 + (0 * 4 + g)) * NC + cl] : 0.0f;
        split8(wv, bhi0, blo0);
#pragma unroll
        for (int i = 0; i < 8; ++i)
            wv[i] = real[1] ? wq[(i * 9 + (1 * 4 + g)) * NC + cl] : 0.0f;
        split8(wv, bhi1, blo1);
#pragma unroll
        for (int i = 0; i < 8; ++i)
            wv[i] = real[2] ? wq[(i * 9 + (2 * 4 + g)) * NC + cl] : 0.0f;
        split8(wv, bhi2, blo2);
    }

    __syncthreads();

    const float4 bias4 = ((const float4*)(bias_all + b * NC))[g];
    const int y = yb0 + wid;
    const size_t orow = ((size_t)(b * HH + y) * WW) * NC;

#pragma unroll 1
    for (int tx = 0; tx < 7; ++tx) {
        const int x0 = xb0 + tx * 16;
        f32x4 accM = {bias4.x, bias4.y, bias4.z, bias4.w};   // hi*hi
        f32x4 accL = {0.f, 0.f, 0.f, 0.f};                   // hiW*loA
        f32x4 accH = {0.f, 0.f, 0.f, 0.f};                   // loW*hiA

#pragma unroll
        for (int c = 0; c < 3; ++c) {
            const int j = tx * 16 + cl + dxL[c];             // 0..113
            const int r = wid + dyL[c];                      // 0..3
            const short8 ahi = lsA[r][j][0];
            const short8 alo = lsA[r][j][1];
            const short8 bh = (c == 0) ? bhi0 : (c == 1) ? bhi1 : bhi2;
            const short8 bl = (c == 0) ? blo0 : (c == 1) ? blo1 : blo2;
            accM = __builtin_amdgcn_mfma_f32_16x16x32_bf16(bh, ahi, accM, 0, 0, 0);
            accL = __builtin_amdgcn_mfma_f32_16x16x32_bf16(bh, alo, accL, 0, 0, 0);
            accH = __builtin_amdgcn_mfma_f32_16x16x32_bf16(bl, ahi, accH, 0, 0, 0);
        }

        // ---- epilogue: elu + ONE float4 store (4 channels of pixel x0+cl) --
        float4 res;
        res.x = elu_f(accM[0] + accL[0] + accH[0]);
        res.y = elu_f(accM[1] + accL[1] + accH[1]);
        res.z = elu_f(accM[2] + accL[2] + accH[2]);
        res.w = elu_f(accM[3] + accL[3] + accH[3]);
        ((float4*)(out + orow + (size_t)(x0 + cl) * NC))[g] = res;
    }
}

extern "C" void kernel_launch(void* const* d_in, const int* in_sizes, int n_in,
                              void* d_out, int out_size, void* d_ws, size_t ws_size,
                              hipStream_t stream) {
    const float* inpt = (const float*)d_in[0];
    const float* fi   = (const float*)d_in[1];
    const float* W1   = (const float*)d_in[2];
    const float* b1   = (const float*)d_in[3];
    const float* Wd   = (const float*)d_in[4];
    const float* bd   = (const float*)d_in[5];
    const float* Wb   = (const float*)d_in[6];
    const float* bb   = (const float*)d_in[7];
    const float* dfn  = (const float*)d_in[8];
    float* out = (float*)d_out;

    float* ws    = (float*)d_ws;
    float* hp    = ws;                        // 4*16*256 = 16384 floats
    float* wDyn  = ws + 16384;                // 16*1152  = 18432 floats
    float* biasA = ws + 16384 + 18432;        // 16*16    = 256 floats
    unsigned* flags = (unsigned*)(ws + 16384 + 18432 + 256);   // 128 u32

    k_hd<<<128, 128, 0, stream>>>(fi, W1, b1, bd, bb, dfn, Wd, Wb,
                                  hp, wDyn, biasA, flags);
    k_conv<<<dim3(2, 112, BN), 128, 0, stream>>>(inpt, wDyn, biasA, out);
}

// Round 21
// 46.186 us; speedup vs baseline: 4.7249x; 1.0024x over previous
//
#include <hip/hip_runtime.h>
#include <math.h>

// Problem constants
constexpr int BN  = 16;    // batch
constexpr int HH  = 224;
constexpr int WW  = 224;
constexpr int CI  = 8;     // input channels
constexpr int FF  = 256;   // filter feature dim
constexpr int NC  = 16;    // output channels
constexpr int NP  = 1152;  // CI*NC*3*3 dynamic params per sample
// reference patch index p = cin*9 + dy*3 + dx ; w[b][p][c] = dyn[b][p*16+c]
// MFMA K-ordering: k = tap*8 + cin, tap = dy*3+dx (taps 9..11 pad=0)
//
// r20 failed the post-timing determinism check (cross-kernel init+atomicAdd).
// This round: SAME kernel geometry, but k_dyn writes k-split PARTIALS to
// separate buffers (plain, unique-address stores — order-independent), and
// k_conv folds bd + 4 partials during its once-per-block B-setup. No atomics,
// no cross-kernel init dependency; every workspace byte rewritten every call.

typedef __attribute__((ext_vector_type(8))) short short8;   // 8 bf16 = 4 VGPR
typedef __attribute__((ext_vector_type(4))) float f32x4;

__device__ __forceinline__ float elu_f(float x) {
    return x > 0.0f ? x : (__expf(x) - 1.0f);
}

// split f32 -> bf16 hi (truncate) + bf16 lo (residual, truncate): v ~= hi+lo
__device__ __forceinline__ void split8(const float* v, short8& hi, short8& lo) {
#pragma unroll
    for (int j = 0; j < 8; ++j) {
        const unsigned u = __float_as_uint(v[j]);
        hi[j] = (short)(u >> 16);
        const float hf = __uint_as_float(u & 0xffff0000u);
        lo[j] = (short)(__float_as_uint(v[j] - hf) >> 16);
    }
}

// -------- kernel 1: h partials, k-split x4 (hp[ks][b][col], pre-elu) ---------
// [r16-proven body, ~1.7 us measured] grid 128 blocks = (b, half, ks).
// Init removed (no atomics downstream anymore).
__global__ __launch_bounds__(128) void k_h(const float* __restrict__ fi,
                                           const float* __restrict__ W1,
                                           const float* __restrict__ b1,
                                           float* __restrict__ hp) {
    __shared__ float x[64];
    const int bid  = blockIdx.x;
    const int b    = bid >> 3;
    const int half = (bid >> 2) & 1;
    const int ks   = bid & 3;
    const int t    = threadIdx.x;

    if (t < 64) x[t] = fi[b * FF + ks * 64 + t];
    __syncthreads();

    const int col = half * 128 + t;
    float acc = (ks == 0) ? b1[col] : 0.0f;
#pragma unroll 8
    for (int k = 0; k < 64; ++k)
        acc = fmaf(x[k], W1[(ks * 64 + k) * FF + col], acc);
    hp[(ks * BN + b) * FF + col] = acc;
}

// ---- kernel 2: dyn/bias k-split PARTIALS (plain stores, no atomics) --------
// grid 576 blocks = 16 samples x 9 col-groups x 4 k-splits (64 k), 128 thr.
// Block stages hs[64] = elu(sum of 4 hp partials); each thread owns ONE
// output column: 64 coalesced Wd loads + 64 FMA -> ONE plain store into
// wPart[ks][b][i]. Deterministic: every element written by exactly one thread.
__global__ __launch_bounds__(128) void k_dyn(const float* __restrict__ hp,
                                             const float* __restrict__ Wd,
                                             const float* __restrict__ Wb,
                                             float* __restrict__ wPart,
                                             float* __restrict__ biasPart) {
    __shared__ float hs[64];
    const int bid = blockIdx.x;
    const int b   = bid / 36;                // sample
    const int r   = bid - b * 36;
    const int cg  = r >> 2;                  // column group (128 cols), 0..8
    const int ks  = r & 3;                   // k-split (64 k)
    const int k0  = ks * 64;
    const int t   = threadIdx.x;

    if (t < 64) {
        const int o = b * FF + k0 + t;
        const float s = hp[o] + hp[BN * FF + o] +
                        hp[2 * BN * FF + o] + hp[3 * BN * FF + o];
        hs[t] = elu_f(s);
    }
    __syncthreads();

    const int i = cg * 128 + t;              // output column < 1152
    float acc = 0.0f;
#pragma unroll 8
    for (int kk = 0; kk < 64; ++kk)
        acc = fmaf(hs[kk], Wd[(size_t)(k0 + kk) * NP + i], acc);
    wPart[(size_t)ks * BN * NP + b * NP + i] = acc;

    if (cg == 0 && t < NC) {                 // bias partial rides along here
        float s = 0.0f;
#pragma unroll 8
        for (int kk = 0; kk < 64; ++kk)
            s = fmaf(hs[kk], Wb[(size_t)(k0 + kk) * NC + t], s);
        biasPart[ks * BN * NC + b * NC + t] = s;
    }
}

// ---------------- kernel 3: dynamic conv as per-sample MFMA GEMM -------------
// [r17 body, ~14.3 us ~ 1.15x memory floor] + B-setup folds bd + 4 wPart
// planes (and bb+dfn+4 biasPart) — once per block, L2-hot.
__global__ __launch_bounds__(128) void k_conv(const float* __restrict__ in,
                                              const float* __restrict__ wPart,
                                              const float* __restrict__ biasPart,
                                              const float* __restrict__ bd,
                                              const float* __restrict__ bb,
                                              const float* __restrict__ dfn,
                                              float* __restrict__ out) {
    __shared__ short8 lsA[4][116][2];        // [row][px][hi/lo] = 14,848 B

    const int b    = blockIdx.z;
    const int half = blockIdx.x;             // 0/1: x-half of the rows
    const int t    = threadIdx.x;
    const int wid  = t >> 6;
    const int lane = t & 63;
    const int cl   = lane & 15;
    const int g    = lane >> 4;              // k-group 0..3
    const int yb0  = blockIdx.y * 2;
    const int xb0  = half * 112;

    // ---- stage 4 rows x 114 px (hi/lo pre-split, zero-filled halo) ----
    for (int s = t; s < 456; s += 128) {
        const int r  = s / 114;
        const int j  = s - r * 114;
        const int gy = yb0 - 1 + r;
        const int gx = xb0 - 1 + j;
        const bool ok = ((unsigned)gy < (unsigned)HH) &&
                        ((unsigned)gx < (unsigned)WW);
        float av[8] = {0.f, 0.f, 0.f, 0.f, 0.f, 0.f, 0.f, 0.f};
        if (ok) {
            const float4* pp =
                (const float4*)(in + ((size_t)(b * HH + gy) * WW + gx) * CI);
            const float4 a0 = pp[0];
            const float4 a1 = pp[1];
            av[0] = a0.x; av[1] = a0.y; av[2] = a0.z; av[3] = a0.w;
            av[4] = a1.x; av[5] = a1.y; av[6] = a1.z; av[7] = a1.w;
        }
        short8 hi, lo;
        split8(av, hi, lo);
        lsA[r][j][0] = hi;
        lsA[r][j][1] = lo;
    }

    // ---- per-lane tap geometry for the 3 k-chunks ----
    int  dyL[3], dxL[3];
    bool real[3];
#pragma unroll
    for (int c = 0; c < 3; ++c) {
        const int tap = c * 4 + g;
        real[c] = (tap < 9);
        const int tp = real[c] ? tap : 0;
        dyL[c] = tp / 3;
        dxL[c] = tp - 3 * dyL[c];
    }

    // ---- weight fragments (hi/lo): fold bd + 4 k-split partials ----
    const float* __restrict__ wp0 = wPart + (size_t)b * NP;   // ks-plane stride BN*NP
    short8 bhi0, blo0, bhi1, blo1, bhi2, blo2;
    {
        float wv[8];
#pragma unroll
        for (int i = 0; i < 8; ++i) {
            const int idx = (i * 9 + (0 * 4 + g)) * NC + cl;
            wv[i] = real[0] ? (bd[idx] + wp0[idx] + wp0[BN * NP + idx] +
                               wp0[2 * BN * NP + idx] + wp0[3 * BN * NP + idx])
                            : 0.0f;
        }
        split8(wv, bhi0, blo0);
#pragma unroll
        for (int i = 0; i < 8; ++i) {
            const int idx = (i * 9 + (1 * 4 + g)) * NC + cl;
            wv[i] = real[1] ? (bd[idx] + wp0[idx] + wp0[BN * NP + idx] +
                               wp0[2 * BN * NP + idx] + wp0[3 * BN * NP + idx])
                            : 0.0f;
        }
        split8(wv, bhi1, blo1);
#pragma unroll
        for (int i = 0; i < 8; ++i) {
            const int idx = (i * 9 + (2 * 4 + g)) * NC + cl;
            wv[i] = real[2] ? (bd[idx] + wp0[idx] + wp0[BN * NP + idx] +
                               wp0[2 * BN * NP + idx] + wp0[3 * BN * NP + idx])
                            : 0.0f;
        }
        split8(wv, bhi2, blo2);
    }

    // ---- bias: bb + dfn + 4 biasPart planes (channels g*4..g*4+3) ----
    float bias_v[4];
#pragma unroll
    for (int j = 0; j < 4; ++j) {
        const int ch = g * 4 + j;
        bias_v[j] = bb[ch] + dfn[ch] +
                    biasPart[0 * BN * NC + b * NC + ch] +
                    biasPart[1 * BN * NC + b * NC + ch] +
                    biasPart[2 * BN * NC + b * NC + ch] +
                    biasPart[3 * BN * NC + b * NC + ch];
    }

    __syncthreads();

    const int y = yb0 + wid;
    const size_t orow = ((size_t)(b * HH + y) * WW) * NC;

#pragma unroll 1
    for (int tx = 0; tx < 7; ++tx) {
        const int x0 = xb0 + tx * 16;
        f32x4 accM = {bias_v[0], bias_v[1], bias_v[2], bias_v[3]};   // hi*hi
        f32x4 accL = {0.f, 0.f, 0.f, 0.f};                           // hiW*loA
        f32x4 accH = {0.f, 0.f, 0.f, 0.f};                           // loW*hiA

#pragma unroll
        for (int c = 0; c < 3; ++c) {
            const int j = tx * 16 + cl + dxL[c];             // 0..113
            const int r = wid + dyL[c];                      // 0..3
            const short8 ahi = lsA[r][j][0];
            const short8 alo = lsA[r][j][1];
            const short8 bh = (c == 0) ? bhi0 : (c == 1) ? bhi1 : bhi2;
            const short8 bl = (c == 0) ? blo0 : (c == 1) ? blo1 : blo2;
            accM = __builtin_amdgcn_mfma_f32_16x16x32_bf16(bh, ahi, accM, 0, 0, 0);
            accL = __builtin_amdgcn_mfma_f32_16x16x32_bf16(bh, alo, accL, 0, 0, 0);
            accH = __builtin_amdgcn_mfma_f32_16x16x32_bf16(bl, ahi, accH, 0, 0, 0);
        }

        // ---- epilogue: elu + ONE float4 store (4 channels of pixel x0+cl) --
        float4 res;
        res.x = elu_f(accM[0] + accL[0] + accH[0]);
        res.y = elu_f(accM[1] + accL[1] + accH[1]);
        res.z = elu_f(accM[2] + accL[2] + accH[2]);
        res.w = elu_f(accM[3] + accL[3] + accH[3]);
        ((float4*)(out + orow + (size_t)(x0 + cl) * NC))[g] = res;
    }
}

extern "C" void kernel_launch(void* const* d_in, const int* in_sizes, int n_in,
                              void* d_out, int out_size, void* d_ws, size_t ws_size,
                              hipStream_t stream) {
    const float* inpt = (const float*)d_in[0];
    const float* fi   = (const float*)d_in[1];
    const float* W1   = (const float*)d_in[2];
    const float* b1   = (const float*)d_in[3];
    const float* Wd   = (const float*)d_in[4];
    const float* bd   = (const float*)d_in[5];
    const float* Wb   = (const float*)d_in[6];
    const float* bb   = (const float*)d_in[7];
    const float* dfn  = (const float*)d_in[8];
    float* out = (float*)d_out;

    float* ws       = (float*)d_ws;
    float* hp       = ws;                       // 4*16*256  = 16384 floats
    float* wPart    = ws + 16384;               // 4*16*1152 = 73728 floats
    float* biasPart = ws + 16384 + 73728;       // 4*16*16   = 1024 floats

    k_h  <<<128, 128, 0, stream>>>(fi, W1, b1, hp);
    k_dyn<<<576, 128, 0, stream>>>(hp, Wd, Wb, wPart, biasPart);
    k_conv<<<dim3(2, 112, BN), 128, 0, stream>>>(inpt, wPart, biasPart,
                                                 bd, bb, dfn, out);
}